// Round 5
// baseline (121.936 us; speedup 1.0000x reference)
//
#include <hip/hip_runtime.h>

typedef float f32x4 __attribute__((ext_vector_type(4)));
typedef short s16x8 __attribute__((ext_vector_type(8)));

#define QSTEP 25.5f
#define DZ (85.0f/512.0f)

// round-to-nearest-even fp32 -> bf16 (low 16 bits)
__device__ __forceinline__ unsigned rne_bf16(float x) {
  unsigned u = __float_as_uint(x);
  return (u + 0x7FFFu + ((u >> 16) & 1u)) >> 16;
}

// Raw fragment-direct load of one 32x32 tile in B-layout order:
// xr[nj*8+j] = X[k0+j][nj*16+col]   (4x64B segments per instr, fully coalesced)
__device__ __forceinline__ void load_raw(const float* __restrict__ g,
                                         int col, int k0, float* xr) {
#pragma unroll
  for (int nj = 0; nj < 2; ++nj)
#pragma unroll
    for (int j = 0; j < 8; ++j)
      xr[nj * 8 + j] = g[(k0 + j) * 32 + nj * 16 + col];
}

// One wave processes 4 consecutive tiles, software-pipelined (prefetch t+1's
// global loads before computing t). Verified 16x16x32 bf16 MFMA layouts:
//   A[m=lane&15 (+16*mi)][k=quad*8+j] ; B[k=quad*8+j][n=lane&15 (+16*nj)]
//   D[row=quad*4+r (+16*mi)][col=lane&15 (+16*nj)]
// Chain (coeff = C@X@C^T ; W = quant(coeff) ; rec = (C@W@C)/1023):
//   S1: tmp = C@X          A=C(hi,lo) static, B=X global frag loads (split)
//   S2: coeff = tmp@C^T    A=tmp (packed-split LDS plane), B = C-row frags
//   S3: U^T = W^T@C^T      A=W^T bf16 plane (b128), B = C-row frags
//   S4: rec = U@C          A=U bf16 plane (b128),   B = C-col frags
__global__ __launch_bounds__(256, 4) void vvc_mfma3_kernel(
    const float* __restrict__ resid,
    const float* __restrict__ dct,
    const float* __restrict__ cshift,
    float* __restrict__ out)
{
  __shared__ float shm[64 + 4 * 1152];   // Sh(64) + per-wave 1152-f32 buffer
  float* Sh   = shm;
  float* Pall = shm + 64;

  const int tid  = threadIdx.x;
  const int wave = tid >> 6;
  const int lane = tid & 63;
  const int col  = lane & 15;
  const int quad = lane >> 4;
  const int k0   = quad * 8;

  // ---- init: C hi/lo planes + C^T hi plane (u16, stride 40 => 16B-aligned rows)
  unsigned short* Chi  = (unsigned short*)Pall;        // [32][40]
  unsigned short* Clo  = Chi + 1280;
  unsigned short* CThi = Chi + 2560;
  {
    float4 cv = ((const float4*)dct)[tid];
    int k = tid >> 3, h = (tid & 7) * 4;
    float vals[4] = {cv.x, cv.y, cv.z, cv.w};
#pragma unroll
    for (int i = 0; i < 4; ++i) {
      unsigned hi = rne_bf16(vals[i]);
      float r = vals[i] - __uint_as_float(hi << 16);
      unsigned lo = rne_bf16(r);
      Chi[k * 40 + h + i]    = (unsigned short)hi;
      Clo[k * 40 + h + i]    = (unsigned short)lo;
      CThi[(h + i) * 40 + k] = (unsigned short)hi;
    }
    if (tid < 64) Sh[tid] = cshift[tid];
  }
  __syncthreads();

  // ---- static fragments (24 VGPRs)
  s16x8 aChi[2], aClo[2], bCThi[2];
#pragma unroll
  for (int i = 0; i < 2; ++i) {
    aChi[i]  = *(const s16x8*)(Chi  + (16 * i + col) * 40 + k0);
    aClo[i]  = *(const s16x8*)(Clo  + (16 * i + col) * 40 + k0);
    bCThi[i] = *(const s16x8*)(CThi + (16 * i + col) * 40 + k0);
  }
  __syncthreads();   // C planes dead; region becomes per-wave buffers

  float* Pw = Pall + wave * 1152;
  const int tile0 = (blockIdx.x * 4 + wave) * 4;   // 4 tiles per wave

  float xbuf[2][16];
  load_raw(resid + (size_t)tile0 * 1024, col, k0, xbuf[0]);

#pragma unroll
  for (int t = 0; t < 4; ++t) {
    // ---- prefetch next tile's raw fragments (hides HBM latency behind compute)
    if (t < 3)
      load_raw(resid + (size_t)(tile0 + t + 1) * 1024, col, k0, xbuf[(t + 1) & 1]);

    const float* xr = xbuf[t & 1];
    float* gout = out + (size_t)(tile0 + t) * 1024;

    // ---- split current X to bf16 hi/lo fragments (truncation split, exact resid)
    s16x8 bXhi[2], bXlo[2];
#pragma unroll
    for (int nj = 0; nj < 2; ++nj)
#pragma unroll
      for (int j = 0; j < 8; ++j) {
        float x = xr[nj * 8 + j] * 1023.0f;
        unsigned u = __float_as_uint(x);
        float r = x - __uint_as_float(u & 0xFFFF0000u);
        bXhi[nj][j] = (short)(u >> 16);
        bXlo[nj][j] = (short)(__float_as_uint(r) >> 16);
      }

    f32x4 acc[2][2];

    // ---- S1: tmp = C @ X  (3-product split)
#pragma unroll
    for (int mi = 0; mi < 2; ++mi)
#pragma unroll
      for (int nj = 0; nj < 2; ++nj) acc[mi][nj] = (f32x4)0.0f;
#pragma unroll
    for (int mi = 0; mi < 2; ++mi)
#pragma unroll
      for (int nj = 0; nj < 2; ++nj) {
        acc[mi][nj] = __builtin_amdgcn_mfma_f32_16x16x32_bf16(aChi[mi], bXhi[nj], acc[mi][nj], 0, 0, 0);
        acc[mi][nj] = __builtin_amdgcn_mfma_f32_16x16x32_bf16(aClo[mi], bXhi[nj], acc[mi][nj], 0, 0, 0);
        acc[mi][nj] = __builtin_amdgcn_mfma_f32_16x16x32_bf16(aChi[mi], bXlo[nj], acc[mi][nj], 0, 0, 0);
      }

    // ---- tmp packed-split plane T[k][w], f32 stride 36
    unsigned* T = (unsigned*)Pw;
#pragma unroll
    for (int mi = 0; mi < 2; ++mi)
#pragma unroll
      for (int nj = 0; nj < 2; ++nj)
#pragma unroll
        for (int r = 0; r < 4; ++r) {
          float v = acc[mi][nj][r];
          unsigned u = __float_as_uint(v);
          float rr = v - __uint_as_float(u & 0xFFFF0000u);
          T[(16 * mi + 4 * quad + r) * 36 + 16 * nj + col] =
              (u >> 16) | (__float_as_uint(rr) & 0xFFFF0000u);
        }

    // ---- S2: coeff = tmp @ C^T
    s16x8 tHi[2], tLo[2];
#pragma unroll
    for (int mi = 0; mi < 2; ++mi) {
      const unsigned* row = T + (16 * mi + col) * 36 + k0;
      uint4 u0 = *(const uint4*)row, u1 = *(const uint4*)(row + 4);
      s16x8 h, l;
      h[0]=(short)u0.x; h[1]=(short)u0.y; h[2]=(short)u0.z; h[3]=(short)u0.w;
      h[4]=(short)u1.x; h[5]=(short)u1.y; h[6]=(short)u1.z; h[7]=(short)u1.w;
      l[0]=(short)(u0.x>>16); l[1]=(short)(u0.y>>16); l[2]=(short)(u0.z>>16); l[3]=(short)(u0.w>>16);
      l[4]=(short)(u1.x>>16); l[5]=(short)(u1.y>>16); l[6]=(short)(u1.z>>16); l[7]=(short)(u1.w>>16);
      tHi[mi] = h; tLo[mi] = l;
    }
#pragma unroll
    for (int mi = 0; mi < 2; ++mi)
#pragma unroll
      for (int nj = 0; nj < 2; ++nj) acc[mi][nj] = (f32x4)0.0f;
#pragma unroll
    for (int mi = 0; mi < 2; ++mi)
#pragma unroll
      for (int nj = 0; nj < 2; ++nj) {
        acc[mi][nj] = __builtin_amdgcn_mfma_f32_16x16x32_bf16(tHi[mi], aChi[nj], acc[mi][nj], 0, 0, 0);
        acc[mi][nj] = __builtin_amdgcn_mfma_f32_16x16x32_bf16(tLo[mi], aChi[nj], acc[mi][nj], 0, 0, 0);
        acc[mi][nj] = __builtin_amdgcn_mfma_f32_16x16x32_bf16(tHi[mi], aClo[nj], acc[mi][nj], 0, 0, 0);
      }

    // ---- quant + dequant; write W^T[l][k] bf16 plane (u16 stride 40)
    unsigned short* WT = (unsigned short*)Pw;
#pragma unroll
    for (int mi = 0; mi < 2; ++mi)
#pragma unroll
      for (int nj = 0; nj < 2; ++nj) {
        unsigned w16[4];
#pragma unroll
        for (int r = 0; r < 4; ++r) {
          float cc  = acc[mi][nj][r];
          float qa  = floorf(fabsf(cc) * (1.0f / QSTEP) + DZ);
          float ca  = qa * QSTEP;
          int   qi  = (int)qa; qi = qi > 63 ? 63 : qi;
          float cs  = Sh[qi];
          float ca2 = (qa + 1.0f) * QSTEP;
          float corr = ((1024.0f - cs) * ca + cs * ca2) * (1.0f / 1024.0f);
          float cah  = (qa < 64.0f) ? corr : ca;
          float wv   = (cc < 0.0f) ? -cah : cah;
          w16[r] = rne_bf16(wv);
        }
        uint2 pk; pk.x = w16[0] | (w16[1] << 16); pk.y = w16[2] | (w16[3] << 16);
        *(uint2*)(WT + (16 * nj + col) * 40 + 16 * mi + 4 * quad) = pk;
      }

    // ---- S3: U^T = W^T @ C^T
    s16x8 wA[2];
#pragma unroll
    for (int mi = 0; mi < 2; ++mi)
      wA[mi] = *(const s16x8*)(WT + (16 * mi + col) * 40 + k0);
#pragma unroll
    for (int mi = 0; mi < 2; ++mi)
#pragma unroll
      for (int nj = 0; nj < 2; ++nj) acc[mi][nj] = (f32x4)0.0f;
#pragma unroll
    for (int mi = 0; mi < 2; ++mi)
#pragma unroll
      for (int nj = 0; nj < 2; ++nj)
        acc[mi][nj] = __builtin_amdgcn_mfma_f32_16x16x32_bf16(wA[mi], aChi[nj], acc[mi][nj], 0, 0, 0);

    // store U[h][w] plane ([D-col][D-row])
    unsigned short* U = WT;   // overlay (WT dead after wA loads)
#pragma unroll
    for (int mi = 0; mi < 2; ++mi)
#pragma unroll
      for (int nj = 0; nj < 2; ++nj) {
        unsigned u16v[4];
#pragma unroll
        for (int r = 0; r < 4; ++r) u16v[r] = rne_bf16(acc[mi][nj][r]);
        uint2 pk; pk.x = u16v[0] | (u16v[1] << 16); pk.y = u16v[2] | (u16v[3] << 16);
        *(uint2*)(U + (16 * nj + col) * 40 + 16 * mi + 4 * quad) = pk;
      }

    // ---- S4: rec = U @ C
    s16x8 uA[2];
#pragma unroll
    for (int mi = 0; mi < 2; ++mi)
      uA[mi] = *(const s16x8*)(U + (16 * mi + col) * 40 + k0);
#pragma unroll
    for (int mi = 0; mi < 2; ++mi)
#pragma unroll
      for (int nj = 0; nj < 2; ++nj) acc[mi][nj] = (f32x4)0.0f;
#pragma unroll
    for (int mi = 0; mi < 2; ++mi)
#pragma unroll
      for (int nj = 0; nj < 2; ++nj)
        acc[mi][nj] = __builtin_amdgcn_mfma_f32_16x16x32_bf16(uA[mi], bCThi[nj], acc[mi][nj], 0, 0, 0);

    // ---- epilogue: /1023 via O plane (f32 stride 36), coalesced float4 stores
    float* O = Pw;   // overlay (U dead after uA loads)
#pragma unroll
    for (int mi = 0; mi < 2; ++mi)
#pragma unroll
      for (int nj = 0; nj < 2; ++nj)
#pragma unroll
        for (int r = 0; r < 4; ++r)
          O[(16 * mi + 4 * quad + r) * 36 + 16 * nj + col] =
              acc[mi][nj][r] * (1.0f / 1023.0f);
#pragma unroll
    for (int m = 0; m < 4; ++m) {
      int f = m * 64 + lane;
      int h = f >> 3, w = (f & 7) * 4;
      ((float4*)gout)[f] = *(const float4*)(O + h * 36 + w);
    }
    // per-wave DS ops are in-order: next iteration's T-pack writes cannot pass
    // this iteration's O reads; no barrier needed.
  }
}

extern "C" void kernel_launch(void* const* d_in, const int* in_sizes, int n_in,
                              void* d_out, int out_size, void* d_ws, size_t ws_size,
                              hipStream_t stream) {
  const float* resid  = (const float*)d_in[0];   // [256,64,32,32]
  const float* dct    = (const float*)d_in[1];   // [32,32]
  const float* cshift = (const float*)d_in[2];   // [64]
  float* out = (float*)d_out;

  int tiles  = out_size / 1024;   // 16384
  int blocks = tiles / 16;        // 4 waves/block x 4 tiles/wave
  vvc_mfma3_kernel<<<blocks, 256, 0, stream>>>(resid, dct, cshift, out);
}